// Round 8
// baseline (232.808 us; speedup 1.0000x reference)
//
#include <hip/hip_runtime.h>
#include <cstddef>

typedef unsigned short u16;
typedef unsigned int u32;
typedef __attribute__((ext_vector_type(8))) __bf16 bf16x8;
typedef __attribute__((ext_vector_type(4))) float f32x4;

constexpr int kB = 8, kC = 256, kCI = 128, kN = 4096, kM = 1024;
constexpr int kCH = 64, kNCH = kM / kCH;
constexpr float kEPS = 1e-5f;
constexpr float kLOG2E = 1.44269504088896f;

__device__ __forceinline__ u16 f2bf(float f) {
    u32 u = __float_as_uint(f);
    u32 r = (u + 0x7fffu + ((u >> 16) & 1u)) >> 16;
    return (u16)r;
}

__device__ __forceinline__ void gload_lds16(const u16* g, u16* l) {
    __builtin_amdgcn_global_load_lds(
        (const __attribute__((address_space(1))) void*)g,
        (__attribute__((address_space(3))) void*)l, 16, 0, 0);
}

// ---------------------------------------------------------------------------
// prep: weights -> bf16; fold BN scale into Ww; bb = (bw-mean)*sc+beta
// Wth/bth scaled by log2(e) so softmax runs in exp2 domain.
// ---------------------------------------------------------------------------
__global__ __launch_bounds__(256) void prep_kernel(const float* __restrict__ Wth,
                                                   const float* __restrict__ bth,
                                                   const float* __restrict__ Wph,
                                                   const float* __restrict__ Wg,
                                                   const float* __restrict__ Ww,
                                                   const float* __restrict__ bw,
                                                   const float* __restrict__ gamma,
                                                   const float* __restrict__ beta,
                                                   const float* __restrict__ mean,
                                                   const float* __restrict__ var,
                                                   u16* __restrict__ Wthb,
                                                   u16* __restrict__ Wphb,
                                                   u16* __restrict__ Wgb,
                                                   u16* __restrict__ Wwsb,
                                                   float* __restrict__ bb,
                                                   float* __restrict__ bthl) {
    int idx = blockIdx.x * 256 + threadIdx.x;
    if (idx < 32768) {
        Wthb[idx] = f2bf(Wth[idx] * kLOG2E);
        if (idx < kCI) bthl[idx] = bth[idx] * kLOG2E;
    } else if (idx < 65536) {
        int j = idx - 32768; Wphb[j] = f2bf(Wph[j]);
    } else if (idx < 98304) {
        int j = idx - 65536; Wgb[j] = f2bf(Wg[j]);
    } else {
        int j = idx - 98304;
        int co = j >> 7;
        float sc = gamma[co] * rsqrtf(var[co] + kEPS);
        Wwsb[j] = f2bf(Ww[j] * sc);
        if ((j & 127) == 0) bb[co] = (bw[co] - mean[co]) * sc + beta[co];
    }
}

// ---------------------------------------------------------------------------
// Pooled 1x1 convs (phi from q, g from v), 32-px blocks for 2x parallelism:
// grid (32, 8, 2) = 512 blocks (2/CU). 4 waves = 2 px-groups x 2 ci-groups.
// Stage 32px x 256c pooled tile (16KB, swizzled), one barrier, 8 K-steps
// with weight frags direct from global (L2-resident).
// ---------------------------------------------------------------------------
__global__ __launch_bounds__(256, 4) void convpg_kernel(const float* __restrict__ q,
                                                        const float* __restrict__ v,
                                                        const u16* __restrict__ Wphb,
                                                        const u16* __restrict__ Wgb,
                                                        const float* __restrict__ bph,
                                                        const float* __restrict__ bg,
                                                        u16* __restrict__ phi,
                                                        u16* __restrict__ g) {
    __shared__ __align__(16) u16 x_lds[32 * 256];   // 16KB
    int z = blockIdx.z, b = blockIdx.y, n0 = blockIdx.x * 32;
    const float* x = z ? v : q;
    const u16* Wb = z ? Wgb : Wphb;
    const float* bias = z ? bg : bph;
    u16* outp = z ? g : phi;

    int t = threadIdx.x;
    int w = t >> 6, lane = t & 63, l15 = lane & 15, quad = lane >> 4;

    // stage pooled x tile
    int px = t & 31, cgrp = t >> 5;
    int p = n0 + px, ph_ = p >> 5, pw_ = p & 31;
#pragma unroll
    for (int cc = 0; cc < 4; cc++) {
        int cb = cgrp * 4 + cc;
        int c0 = cb * 8;
        float f[8];
#pragma unroll
        for (int j = 0; j < 8; j++) {
            const float* src = x + ((size_t)(b * kC + c0 + j) * 64 + 2 * ph_) * 64
                               + 2 * pw_;
            float2 a = *(const float2*)src;
            float2 b2 = *(const float2*)(src + 64);
            f[j] = 0.25f * (a.x + a.y + b2.x + b2.y);
        }
        uint4 pk;
        pk.x = (u32)f2bf(f[0]) | ((u32)f2bf(f[1]) << 16);
        pk.y = (u32)f2bf(f[2]) | ((u32)f2bf(f[3]) << 16);
        pk.z = (u32)f2bf(f[4]) | ((u32)f2bf(f[5]) << 16);
        pk.w = (u32)f2bf(f[6]) | ((u32)f2bf(f[7]) << 16);
        *(uint4*)&x_lds[px * 256 + ((cb ^ (px & 7)) * 8)] = pk;
    }
    __syncthreads();

    int px_h = w >> 1, ci_h = w & 1;
    f32x4 acc[4];
#pragma unroll
    for (int i = 0; i < 4; i++) acc[i] = (f32x4){0.f, 0.f, 0.f, 0.f};

    int rpx = px_h * 16 + l15;
#pragma unroll
    for (int ks = 0; ks < 8; ks++) {
        bf16x8 xf = *(const bf16x8*)&x_lds[rpx * 256 +
                                           (((ks * 4 + quad) ^ (rpx & 7)) * 8)];
#pragma unroll
        for (int ct = 0; ct < 4; ct++) {
            int ci = ci_h * 64 + ct * 16 + l15;
            bf16x8 wf = *(const bf16x8*)&Wb[ci * kC + ks * 32 + quad * 8];
            if (z)
                acc[ct] = __builtin_amdgcn_mfma_f32_16x16x32_bf16(xf, wf, acc[ct], 0, 0, 0);
            else
                acc[ct] = __builtin_amdgcn_mfma_f32_16x16x32_bf16(wf, xf, acc[ct], 0, 0, 0);
        }
    }

    if (!z) {   // phi: n-major
        int opx = n0 + px_h * 16 + l15;
#pragma unroll
        for (int ct = 0; ct < 4; ct++) {
            int ci0 = ci_h * 64 + ct * 16 + quad * 4;
            uint2 pk;
            pk.x = (u32)f2bf(acc[ct][0] + bias[ci0 + 0]) |
                   ((u32)f2bf(acc[ct][1] + bias[ci0 + 1]) << 16);
            pk.y = (u32)f2bf(acc[ct][2] + bias[ci0 + 2]) |
                   ((u32)f2bf(acc[ct][3] + bias[ci0 + 3]) << 16);
            *(uint2*)&outp[(size_t)(b * kM + opx) * kCI + ci0] = pk;
        }
    } else {    // g: ci-major
        int opx = n0 + px_h * 16 + quad * 4;
#pragma unroll
        for (int ct = 0; ct < 4; ct++) {
            int ci = ci_h * 64 + ct * 16 + l15;
            float bs = bias[ci];
            uint2 pk;
            pk.x = (u32)f2bf(acc[ct][0] + bs) | ((u32)f2bf(acc[ct][1] + bs) << 16);
            pk.y = (u32)f2bf(acc[ct][2] + bs) | ((u32)f2bf(acc[ct][3] + bs) << 16);
            *(uint2*)&outp[(size_t)(b * kCI + ci) * kM + opx] = pk;
        }
    }
}

// ---------------------------------------------------------------------------
// FUSED theta-conv + attention + final conv.
// Prologue: stage k tile (64px x 256c) into ph_lds area, 64 MFMA/wave with
// Wth frags direct from L2, +bth -> theta tile in LDS ([64][136] padded,
// wave-local rows so no extra barrier) -> thf regs.
// Main loop: r7 structure (async DMA double-buffered phi/g, one barrier per
// chunk, exp2 softmax + defer-max(8), per-wave P LDS, deferred l-reduce).
// Epilogue: y -> LDS -> final 1x1 conv (BN-folded Wws from L2) + bb + v.
// LDS 72KB -> 2 blocks/CU.
// ---------------------------------------------------------------------------
__global__ __launch_bounds__(256) void attn_kernel(const float* __restrict__ k,
                                                   const u16* __restrict__ Wthb,
                                                   const float* __restrict__ bthl,
                                                   const u16* __restrict__ phi,
                                                   const u16* __restrict__ g,
                                                   const u16* __restrict__ Wws,
                                                   const float* __restrict__ bb,
                                                   const float* __restrict__ v,
                                                   float* __restrict__ out) {
    __shared__ __align__(16) u16 ph_lds[2][8192];  // [buf][ks:4][m:64][slot:4][8]
    __shared__ __align__(16) u16 g_lds[2][8192];   // [buf][ks2:2][ci:128][slot:4][8]
    __shared__ __align__(16) u16 p_lds[4096];      // [wave:4][frag:2][col:16][k:32]

    int t = threadIdx.x, b = blockIdx.y, n0 = blockIdx.x * 64;
    int w = t >> 6, lane = t & 63, l15 = lane & 15, quad = lane >> 4;
    int sw = (l15 >> 1) & 3;

    // ---- fused theta conv prologue ----
    bf16x8 thf[4];
    {
        u16* x_lds = &ph_lds[0][0];     // 32KB k staging
        u16* th_lds = &g_lds[0][0];     // [64 n][136 ci] padded (17.4KB, in g area)
        int px = t & 63, cb8 = t >> 6;
        for (int cc8 = 0; cc8 < 8; cc8++) {
            int cb = cb8 * 8 + cc8;
            int c0 = cb * 8;
            float f[8];
#pragma unroll
            for (int j = 0; j < 8; j++)
                f[j] = k[(size_t)(b * kC + c0 + j) * kN + n0 + px];
            uint4 pk;
            pk.x = (u32)f2bf(f[0]) | ((u32)f2bf(f[1]) << 16);
            pk.y = (u32)f2bf(f[2]) | ((u32)f2bf(f[3]) << 16);
            pk.z = (u32)f2bf(f[4]) | ((u32)f2bf(f[5]) << 16);
            pk.w = (u32)f2bf(f[6]) | ((u32)f2bf(f[7]) << 16);
            *(uint4*)&x_lds[px * 256 + ((cb ^ (px & 7)) * 8)] = pk;
        }
        __syncthreads();

        f32x4 acc[8];
#pragma unroll
        for (int i = 0; i < 8; i++) acc[i] = (f32x4){0.f, 0.f, 0.f, 0.f};
        int rpx = w * 16 + l15;
#pragma unroll
        for (int ks = 0; ks < 8; ks++) {
            bf16x8 xf = *(const bf16x8*)&x_lds[rpx * 256 +
                                               (((ks * 4 + quad) ^ (rpx & 7)) * 8)];
#pragma unroll
            for (int ct = 0; ct < 8; ct++) {
                bf16x8 wf = *(const bf16x8*)&Wthb[(ct * 16 + l15) * kC + ks * 32 + quad * 8];
                acc[ct] = __builtin_amdgcn_mfma_f32_16x16x32_bf16(wf, xf, acc[ct], 0, 0, 0);
            }
        }
        // theta[px=w*16+l15][ci] = acc + bth; rows are wave-local -> in-wave
        // LDS ordering suffices (no barrier before the thf read).
#pragma unroll
        for (int ct = 0; ct < 8; ct++) {
            int ci0 = ct * 16 + quad * 4;
            uint2 pk;
            pk.x = (u32)f2bf(acc[ct][0] + bthl[ci0 + 0]) |
                   ((u32)f2bf(acc[ct][1] + bthl[ci0 + 1]) << 16);
            pk.y = (u32)f2bf(acc[ct][2] + bthl[ci0 + 2]) |
                   ((u32)f2bf(acc[ct][3] + bthl[ci0 + 3]) << 16);
            *(uint2*)&th_lds[rpx * 136 + ci0] = pk;
        }
#pragma unroll
        for (int ks = 0; ks < 4; ks++)
            thf[ks] = *(const bf16x8*)&th_lds[rpx * 136 + ks * 32 + quad * 8];
        __syncthreads();   // everyone done with x_lds/th_lds before DMA reuse
    }

    f32x4 oacc[8];
#pragma unroll
    for (int ct = 0; ct < 8; ct++) oacc[ct] = (f32x4){0.f, 0.f, 0.f, 0.f};
    float m_ = -1e30f, l_ = 0.f;

    const u16* phB = phi + (size_t)b * kM * kCI;
    const u16* gB  = g   + (size_t)b * kCI * kM;
    u16* pw = p_lds + w * 1024;

    auto STAGE = [&](int buf, int ch) {
        int c0 = ch * kCH;
#pragma unroll
        for (int i = 0; i < 4; i++) {
            int W = t + 256 * i;
            int ks = W >> 8, m = (W >> 2) & 63, sl = W & 3;
            int cb = (ks << 2) | (sl ^ ((m >> 1) & 3));
            gload_lds16(phB + (size_t)(c0 + m) * kCI + cb * 8,
                        &ph_lds[buf][(w * 64 + i * 256) * 8]);
        }
#pragma unroll
        for (int i = 0; i < 4; i++) {
            int W = t + 256 * i;
            int ks2 = W >> 9, ci = (W >> 2) & 127, sl = W & 3;
            int mb = (ks2 << 2) | (sl ^ ((ci >> 1) & 3));
            gload_lds16(gB + (size_t)ci * kM + c0 + mb * 8,
                        &g_lds[buf][(w * 64 + i * 256) * 8]);
        }
    };

    STAGE(0, 0);

    for (int ch = 0; ch < kNCH; ++ch) {
        asm volatile("s_waitcnt vmcnt(0)" ::: "memory");
        __syncthreads();   // chunk ch landed; all reads of target buf done
        if (ch + 1 < kNCH) STAGE((ch + 1) & 1, ch + 1);
        const u16* phb = ph_lds[ch & 1];
        const u16* glb = g_lds[ch & 1];

        // S' = phi(64m x 128k) . theta^T : 4 mt-tiles, C-col = n (exp2 dom)
        f32x4 sacc[4];
#pragma unroll
        for (int mt = 0; mt < 4; mt++) sacc[mt] = (f32x4){0.f, 0.f, 0.f, 0.f};
#pragma unroll
        for (int ks = 0; ks < 4; ks++)
#pragma unroll
            for (int mt = 0; mt < 4; mt++) {
                bf16x8 a = *(const bf16x8*)&phb[ks * 2048 + (mt * 16 + l15) * 32 +
                                                ((quad ^ sw) * 8)];
                sacc[mt] = __builtin_amdgcn_mfma_f32_16x16x32_bf16(a, thf[ks], sacc[mt], 0, 0, 0);
            }

        // online softmax (exp2 domain, defer-max(8), per-lane partial l)
        float mc = -1e30f;
#pragma unroll
        for (int mt = 0; mt < 4; mt++)
#pragma unroll
            for (int r = 0; r < 4; r++) mc = fmaxf(mc, sacc[mt][r]);
        mc = fmaxf(mc, __shfl_xor(mc, 16, 64));
        mc = fmaxf(mc, __shfl_xor(mc, 32, 64));
        if (__any(mc > m_ + 8.0f)) {
            float mn = fmaxf(m_, mc);
            float al = exp2f(m_ - mn);
            m_ = mn;
            l_ *= al;
#pragma unroll
            for (int ct = 0; ct < 8; ct++)
#pragma unroll
                for (int r = 0; r < 4; r++) oacc[ct][r] *= al;
        }
        float rs = 0.f;
#pragma unroll
        for (int mt = 0; mt < 4; mt++)
#pragma unroll
            for (int r = 0; r < 4; r++) {
                float p = exp2f(sacc[mt][r] - m_);
                sacc[mt][r] = p;
                rs += p;
            }
        l_ += rs;

        // scatter P' -> per-wave frag LDS
#pragma unroll
        for (int mt = 0; mt < 4; mt++)
#pragma unroll
            for (int h = 0; h < 2; h++) {
                u32 d = (u32)f2bf(sacc[mt][2 * h]) | ((u32)f2bf(sacc[mt][2 * h + 1]) << 16);
                int m = mt * 16 + quad * 4 + 2 * h;
                int frag = m >> 5;
                int kblk = ((m >> 3) & 3);
                int j = (quad & 1) * 4 + 2 * h;
                *(u32*)&pw[frag * 512 + l15 * 32 + ((kblk ^ sw) * 8) + j] = d;
            }

        // O' += G^T(128ci x 64m) . P'
#pragma unroll
        for (int ks2 = 0; ks2 < 2; ks2++) {
            bf16x8 bfrag = *(const bf16x8*)&pw[ks2 * 512 + l15 * 32 + ((quad ^ sw) * 8)];
#pragma unroll
            for (int ct = 0; ct < 8; ct++) {
                bf16x8 a = *(const bf16x8*)&glb[ks2 * 4096 + (ct * 16 + l15) * 32 +
                                                ((quad ^ sw) * 8)];
                oacc[ct] = __builtin_amdgcn_mfma_f32_16x16x32_bf16(a, bfrag, oacc[ct], 0, 0, 0);
            }
        }
    }

    // ---- fused final conv epilogue ----
    l_ += __shfl_xor(l_, 16, 64);
    l_ += __shfl_xor(l_, 32, 64);
    float inv = 1.0f / l_;

    __syncthreads();                      // all chunk compute done; LDS free
    u16* y_lds = &ph_lds[0][0];           // [64 n][136 ci-padded] (17KB)
    int nrow = w * 16 + l15;              // C-col = n within tile
#pragma unroll
    for (int ct = 0; ct < 8; ct++) {
        uint2 pk;
        pk.x = (u32)f2bf(oacc[ct][0] * inv) | ((u32)f2bf(oacc[ct][1] * inv) << 16);
        pk.y = (u32)f2bf(oacc[ct][2] * inv) | ((u32)f2bf(oacc[ct][3] * inv) << 16);
        *(uint2*)&y_lds[nrow * 136 + ct * 16 + quad * 4] = pk;
    }
    __syncthreads();

    bf16x8 af[4];
#pragma unroll
    for (int ks = 0; ks < 4; ks++)
        af[ks] = *(const bf16x8*)&y_lds[nrow * 136 + ks * 32 + quad * 8];

#pragma unroll
    for (int ct = 0; ct < 16; ct++) {
        int co = ct * 16 + l15;
        f32x4 a = (f32x4){0.f, 0.f, 0.f, 0.f};
#pragma unroll
        for (int ks = 0; ks < 4; ks++) {
            bf16x8 bf = *(const bf16x8*)&Wws[(size_t)co * kCI + ks * 32 + quad * 8];
            a = __builtin_amdgcn_mfma_f32_16x16x32_bf16(af[ks], bf, a, 0, 0, 0);
        }
        float bbv = bb[co];
        size_t base = (size_t)(b * kC + co) * kN + n0 + w * 16 + quad * 4;
        float4 vv = *(const float4*)&v[base];
        float4 ov;
        ov.x = a[0] + bbv + vv.x;
        ov.y = a[1] + bbv + vv.y;
        ov.z = a[2] + bbv + vv.z;
        ov.w = a[3] + bbv + vv.w;
        *(float4*)&out[base] = ov;
    }
}

// ---------------------------------------------------------------------------
extern "C" void kernel_launch(void* const* d_in, const int* in_sizes, int n_in,
                              void* d_out, int out_size, void* d_ws, size_t ws_size,
                              hipStream_t stream) {
    (void)in_sizes; (void)n_in; (void)out_size; (void)ws_size;
    const float* q     = (const float*)d_in[0];
    const float* k     = (const float*)d_in[1];
    const float* v     = (const float*)d_in[2];
    const float* Wg    = (const float*)d_in[3];
    const float* bg    = (const float*)d_in[4];
    const float* Wth   = (const float*)d_in[5];
    const float* bth   = (const float*)d_in[6];
    const float* Wph   = (const float*)d_in[7];
    const float* bph   = (const float*)d_in[8];
    const float* Ww    = (const float*)d_in[9];
    const float* bw    = (const float*)d_in[10];
    const float* gamma = (const float*)d_in[11];
    const float* beta  = (const float*)d_in[12];
    const float* mean  = (const float*)d_in[13];
    const float* var   = (const float*)d_in[14];
    float* out = (float*)d_out;

    u16* wsu = (u16*)d_ws;
    u16*   phi   = wsu;                       // 1M u16 (2MB)
    u16*   gbuf  = phi + 1048576;             // 1M u16 (2MB)
    u16*   Wthb  = gbuf + 1048576;
    u16*   Wphb  = Wthb + 32768;
    u16*   Wgb   = Wphb + 32768;
    u16*   Wwsb  = Wgb + 32768;
    float* bbuf  = (float*)(Wwsb + 32768);    // 256 f32
    float* bthl  = bbuf + 256;                // 128 f32

    prep_kernel<<<dim3(512), 256, 0, stream>>>(Wth, bth, Wph, Wg, Ww, bw, gamma, beta,
                                               mean, var, Wthb, Wphb, Wgb, Wwsb,
                                               bbuf, bthl);
    convpg_kernel<<<dim3(32, 8, 2), 256, 0, stream>>>(q, v, Wphb, Wgb, bph, bg,
                                                      phi, gbuf);
    attn_kernel<<<dim3(64, 8), 256, 0, stream>>>(k, Wthb, bthl, phi, gbuf,
                                                 Wwsb, bbuf, v, out);
}

// Round 9
// 220.671 us; speedup vs baseline: 1.0550x; 1.0550x over previous
//
#include <hip/hip_runtime.h>
#include <cstddef>

typedef unsigned short u16;
typedef unsigned int u32;
typedef __attribute__((ext_vector_type(8))) __bf16 bf16x8;
typedef __attribute__((ext_vector_type(4))) float f32x4;

constexpr int kB = 8, kC = 256, kCI = 128, kN = 4096, kM = 1024;
constexpr int kHM = 512;            // m per wave-group
constexpr int kCH = 32;             // m per chunk
constexpr int kNCH = kHM / kCH;     // 16 chunks per group
constexpr float kEPS = 1e-5f;
constexpr float kLOG2E = 1.44269504088896f;

__device__ __forceinline__ u16 f2bf(float f) {
    u32 u = __float_as_uint(f);
    u32 r = (u + 0x7fffu + ((u >> 16) & 1u)) >> 16;
    return (u16)r;
}

__device__ __forceinline__ void gload_lds16(const u16* g, u16* l) {
    __builtin_amdgcn_global_load_lds(
        (const __attribute__((address_space(1))) void*)g,
        (__attribute__((address_space(3))) void*)l, 16, 0, 0);
}

// ---------------------------------------------------------------------------
// prep: weights -> bf16; fold BN scale into Ww; bb = (bw-mean)*sc+beta
// Wth/bth scaled by log2(e) so softmax runs in exp2 domain.
// ---------------------------------------------------------------------------
__global__ __launch_bounds__(256) void prep_kernel(const float* __restrict__ Wth,
                                                   const float* __restrict__ bth,
                                                   const float* __restrict__ Wph,
                                                   const float* __restrict__ Wg,
                                                   const float* __restrict__ Ww,
                                                   const float* __restrict__ bw,
                                                   const float* __restrict__ gamma,
                                                   const float* __restrict__ beta,
                                                   const float* __restrict__ mean,
                                                   const float* __restrict__ var,
                                                   u16* __restrict__ Wthb,
                                                   u16* __restrict__ Wphb,
                                                   u16* __restrict__ Wgb,
                                                   u16* __restrict__ Wwsb,
                                                   float* __restrict__ bb,
                                                   float* __restrict__ bthl) {
    int idx = blockIdx.x * 256 + threadIdx.x;
    if (idx < 32768) {
        Wthb[idx] = f2bf(Wth[idx] * kLOG2E);
        if (idx < kCI) bthl[idx] = bth[idx] * kLOG2E;
    } else if (idx < 65536) {
        int j = idx - 32768; Wphb[j] = f2bf(Wph[j]);
    } else if (idx < 98304) {
        int j = idx - 65536; Wgb[j] = f2bf(Wg[j]);
    } else {
        int j = idx - 98304;
        int co = j >> 7;
        float sc = gamma[co] * rsqrtf(var[co] + kEPS);
        Wwsb[j] = f2bf(Ww[j] * sc);
        if ((j & 127) == 0) bb[co] = (bw[co] - mean[co]) * sc + beta[co];
    }
}

// ---------------------------------------------------------------------------
// Whole-K conv1x1 body (r6/r7 form): stage x tile (64 px x 256 c bf16
// swizzled) once, one barrier, 8 K-steps with weight frags direct from
// global (L2-resident).
// ---------------------------------------------------------------------------
template <int POOL>
__device__ __forceinline__ void conv_body(const float* __restrict__ x,
                                          const u16* __restrict__ Wb,
                                          const float* __restrict__ bias,
                                          u16* __restrict__ out, int Mn,
                                          int cmajor, int b, int n0,
                                          u16* x_lds) {
    int t = threadIdx.x;
    int w = t >> 6, lane = t & 63, l15 = lane & 15, quad = lane >> 4;
    int px = t & 63, cb8 = t >> 6;

    for (int cc8 = 0; cc8 < 8; cc8++) {
        int cb = cb8 * 8 + cc8;
        int c0 = cb * 8;
        float f[8];
        if (POOL) {
            int p = n0 + px, ph_ = p >> 5, pw_ = p & 31;
#pragma unroll
            for (int j = 0; j < 8; j++) {
                const float* src = x + ((size_t)(b * kC + c0 + j) * 64
                                        + 2 * ph_) * 64 + 2 * pw_;
                float2 a = *(const float2*)src;
                float2 b2 = *(const float2*)(src + 64);
                f[j] = 0.25f * (a.x + a.y + b2.x + b2.y);
            }
        } else {
#pragma unroll
            for (int j = 0; j < 8; j++)
                f[j] = x[(size_t)(b * kC + c0 + j) * Mn + n0 + px];
        }
        uint4 pk;
        pk.x = (u32)f2bf(f[0]) | ((u32)f2bf(f[1]) << 16);
        pk.y = (u32)f2bf(f[2]) | ((u32)f2bf(f[3]) << 16);
        pk.z = (u32)f2bf(f[4]) | ((u32)f2bf(f[5]) << 16);
        pk.w = (u32)f2bf(f[6]) | ((u32)f2bf(f[7]) << 16);
        *(uint4*)&x_lds[px * 256 + ((cb ^ (px & 7)) * 8)] = pk;
    }
    __syncthreads();

    f32x4 acc[8];
#pragma unroll
    for (int i = 0; i < 8; i++) acc[i] = (f32x4){0.f, 0.f, 0.f, 0.f};

    int rpx = w * 16 + l15;
#pragma unroll
    for (int ks = 0; ks < 8; ks++) {
        bf16x8 xf = *(const bf16x8*)&x_lds[rpx * 256 +
                                           (((ks * 4 + quad) ^ (rpx & 7)) * 8)];
#pragma unroll
        for (int ct = 0; ct < 8; ct++) {
            bf16x8 wf = *(const bf16x8*)&Wb[(ct * 16 + l15) * kC + ks * 32 + quad * 8];
            if (cmajor)
                acc[ct] = __builtin_amdgcn_mfma_f32_16x16x32_bf16(xf, wf, acc[ct], 0, 0, 0);
            else
                acc[ct] = __builtin_amdgcn_mfma_f32_16x16x32_bf16(wf, xf, acc[ct], 0, 0, 0);
        }
    }

    if (cmajor == 0) {
        int opx = n0 + w * 16 + l15;
#pragma unroll
        for (int ct = 0; ct < 8; ct++) {
            int ci0 = ct * 16 + quad * 4;
            uint2 pk;
            pk.x = (u32)f2bf(acc[ct][0] + bias[ci0 + 0]) |
                   ((u32)f2bf(acc[ct][1] + bias[ci0 + 1]) << 16);
            pk.y = (u32)f2bf(acc[ct][2] + bias[ci0 + 2]) |
                   ((u32)f2bf(acc[ct][3] + bias[ci0 + 3]) << 16);
            *(uint2*)&out[(size_t)(b * Mn + opx) * kCI + ci0] = pk;
        }
    } else {
        int opx = n0 + w * 16 + quad * 4;
#pragma unroll
        for (int ct = 0; ct < 8; ct++) {
            int ci = ct * 16 + l15;
            float bs = bias[ci];
            uint2 pk;
            pk.x = (u32)f2bf(acc[ct][0] + bs) | ((u32)f2bf(acc[ct][1] + bs) << 16);
            pk.y = (u32)f2bf(acc[ct][2] + bs) | ((u32)f2bf(acc[ct][3] + bs) << 16);
            *(uint2*)&out[(size_t)(b * kCI + ci) * Mn + opx] = pk;
        }
    }
}

__global__ __launch_bounds__(256, 4) void convs_kernel(const float* __restrict__ q,
                                                       const float* __restrict__ k,
                                                       const float* __restrict__ v,
                                                       const u16* __restrict__ Wthb,
                                                       const u16* __restrict__ Wphb,
                                                       const u16* __restrict__ Wgb,
                                                       const float* __restrict__ bthl,
                                                       const float* __restrict__ bph,
                                                       const float* __restrict__ bg,
                                                       u16* __restrict__ theta,
                                                       u16* __restrict__ phi,
                                                       u16* __restrict__ g) {
    __shared__ __align__(16) u16 x_lds[64 * 256];
    int bx = blockIdx.x, b = blockIdx.y;
    if (bx < 64) {
        conv_body<0>(k, Wthb, bthl, theta, kN, 0, b, bx * 64, x_lds);
    } else {
        int z = (bx >= 80);
        int n0 = (z ? (bx - 80) : (bx - 64)) * 64;
        conv_body<1>(z ? v : q, z ? Wgb : Wphb, z ? bg : bph, z ? g : phi,
                     kM, z, b, n0, x_lds);
    }
}

// ---------------------------------------------------------------------------
// FUSED attention + final conv, 8-wave IN-BLOCK m-split.
// 512 thr: waves 0-3 (grp 0) process m in [0,512), waves 4-7 (grp 1)
// m in [512,1024); 16 chunks of 32 m each; per-wave serial chain per chunk
// is HALF of r7's (8 QK MFMA + softmax-on-8 + 4-wr scatter + 8 PV MFMA).
// Mechanics proven in r7: async global_load_lds double-buffer for phi+g
// (linear LDS dst, inverse-swizzled global src), ONE barrier per chunk,
// exp2 softmax + defer-max(8), per-wave P LDS, deferred l-reduce.
// End: groups combine through LDS (r2-verified math), then the final 1x1
// conv (BN-folded Wws) + bb + v runs on all 8 waves (co split by group).
// LDS: phi 2x2x8KB + g 2x2x8KB + P 8KB + ml = 72.5KB -> 2 blocks/CU
// (16 waves/CU). launch_bounds(512,4) caps regs at 128 (state ~85).
// ---------------------------------------------------------------------------
__global__ __launch_bounds__(512, 4) void attn_kernel(const u16* __restrict__ theta,
                                                      const u16* __restrict__ phi,
                                                      const u16* __restrict__ g,
                                                      const u16* __restrict__ Wws,
                                                      const float* __restrict__ bb,
                                                      const float* __restrict__ v,
                                                      float* __restrict__ out) {
    __shared__ __align__(16) u16 ph_lds[2][2][4096]; // [grp][buf][ks:4][m:32][sl:4][8]
    __shared__ __align__(16) u16 g_lds[2][2][4096];  // [grp][buf][ci:128][sl:4][8]
    __shared__ __align__(16) u16 p_lds[8 * 512];     // per-wave [col:16][k:32]
    __shared__ float mlsh[128];

    int t = threadIdx.x, b = blockIdx.y, n0 = blockIdx.x * 64;
    int w = t >> 6, lane = t & 63, l15 = lane & 15, quad = lane >> 4;
    int grp = w >> 2, wl = w & 3, th = t & 255;
    int sw = (l15 >> 1) & 3;

    // theta B-frags in registers (16 n per wave; groups duplicate)
    bf16x8 thf[4];
    const u16* thB = theta + ((size_t)(b * kN) + n0 + wl * 16 + l15) * kCI;
#pragma unroll
    for (int ks = 0; ks < 4; ks++)
        thf[ks] = *(const bf16x8*)&thB[ks * 32 + quad * 8];

    f32x4 oacc[8];
#pragma unroll
    for (int ct = 0; ct < 8; ct++) oacc[ct] = (f32x4){0.f, 0.f, 0.f, 0.f};
    float m_ = -1e30f, l_ = 0.f;

    const u16* phB = phi + (size_t)b * kM * kCI;
    const u16* gB  = g   + (size_t)b * kCI * kM;
    u16* pw = p_lds + w * 512;

    // async stage chunk ch (32 m) for this group into buf.
    // dst: linear, wave-uniform base + lane*16B; src: inverse-swizzled.
    auto STAGE = [&](int buf, int ch) {
        int c0 = grp * kHM + ch * kCH;
#pragma unroll
        for (int i = 0; i < 2; i++) {
            int W = th + 256 * i;                     // phi slot
            int ks = W >> 7, m = (W >> 2) & 31, sl = W & 3;
            int cb = (ks << 2) | (sl ^ ((m >> 1) & 3));
            gload_lds16(phB + (size_t)(c0 + m) * kCI + cb * 8,
                        &ph_lds[grp][buf][(wl * 64 + i * 256) * 8]);
        }
#pragma unroll
        for (int i = 0; i < 2; i++) {
            int W = th + 256 * i;                     // g slot
            int ci = W >> 2, sl = W & 3;
            int mb = sl ^ ((ci >> 1) & 3);
            gload_lds16(gB + (size_t)ci * kM + c0 + mb * 8,
                        &g_lds[grp][buf][(wl * 64 + i * 256) * 8]);
        }
    };

    STAGE(0, 0);

    for (int ch = 0; ch < kNCH; ++ch) {
        asm volatile("s_waitcnt vmcnt(0)" ::: "memory");
        __syncthreads();   // chunk ch landed; prior reads of target buf done
        if (ch + 1 < kNCH) STAGE((ch + 1) & 1, ch + 1);
        const u16* phb = ph_lds[grp][ch & 1];
        const u16* glb = g_lds[grp][ch & 1];

        // S' = phi(32m x 128k) . theta^T : 2 mt-tiles, C-col = n (exp2 dom)
        f32x4 sacc[2];
#pragma unroll
        for (int mt = 0; mt < 2; mt++) sacc[mt] = (f32x4){0.f, 0.f, 0.f, 0.f};
#pragma unroll
        for (int ks = 0; ks < 4; ks++)
#pragma unroll
            for (int mt = 0; mt < 2; mt++) {
                bf16x8 a = *(const bf16x8*)&phb[ks * 1024 + (mt * 16 + l15) * 32 +
                                                ((quad ^ sw) * 8)];
                sacc[mt] = __builtin_amdgcn_mfma_f32_16x16x32_bf16(a, thf[ks], sacc[mt], 0, 0, 0);
            }

        // online softmax (exp2 domain, defer-max(8), per-lane partial l)
        float mc = -1e30f;
#pragma unroll
        for (int mt = 0; mt < 2; mt++)
#pragma unroll
            for (int r = 0; r < 4; r++) mc = fmaxf(mc, sacc[mt][r]);
        mc = fmaxf(mc, __shfl_xor(mc, 16, 64));
        mc = fmaxf(mc, __shfl_xor(mc, 32, 64));
        if (__any(mc > m_ + 8.0f)) {
            float mn = fmaxf(m_, mc);
            float al = exp2f(m_ - mn);
            m_ = mn;
            l_ *= al;
#pragma unroll
            for (int ct = 0; ct < 8; ct++)
#pragma unroll
                for (int r = 0; r < 4; r++) oacc[ct][r] *= al;
        }
        float rs = 0.f;
#pragma unroll
        for (int mt = 0; mt < 2; mt++)
#pragma unroll
            for (int r = 0; r < 4; r++) {
                float p = exp2f(sacc[mt][r] - m_);
                sacc[mt][r] = p;
                rs += p;
            }
        l_ += rs;

        // scatter P' (32 m) -> per-wave frag LDS
#pragma unroll
        for (int mt = 0; mt < 2; mt++)
#pragma unroll
            for (int h = 0; h < 2; h++) {
                u32 d = (u32)f2bf(sacc[mt][2 * h]) | ((u32)f2bf(sacc[mt][2 * h + 1]) << 16);
                int m = mt * 16 + quad * 4 + 2 * h;
                int kblk = (m >> 3) & 3;
                int j = (quad & 1) * 4 + 2 * h;
                *(u32*)&pw[l15 * 32 + ((kblk ^ sw) * 8) + j] = d;
            }

        // O' += G^T(128ci x 32m) . P'  (single K=32 pass)
        bf16x8 bfrag = *(const bf16x8*)&pw[l15 * 32 + ((quad ^ sw) * 8)];
#pragma unroll
        for (int ct = 0; ct < 8; ct++) {
            bf16x8 a = *(const bf16x8*)&glb[(ct * 16 + l15) * 32 + ((quad ^ sw) * 8)];
            oacc[ct] = __builtin_amdgcn_mfma_f32_16x16x32_bf16(a, bfrag, oacc[ct], 0, 0, 0);
        }
    }

    // ---- cross-group combine + fused final conv ----
    l_ += __shfl_xor(l_, 16, 64);
    l_ += __shfl_xor(l_, 32, 64);

    __syncthreads();                           // all compute done; LDS free
    float* olds = (float*)&ph_lds[0][0][0];    // [64 n][128 ci] f32 (32KB exact)
    u16* y_lds = &g_lds[0][0][0];              // [64 n][136 ci] bf16 (17KB)
    int nl = wl * 16 + l15;
    if (grp == 1) {
#pragma unroll
        for (int ct = 0; ct < 8; ct++) {
            int s = (ct * 4 + quad) ^ (nl & 7);
            *(f32x4*)&olds[nl * 128 + s * 4] = oacc[ct];
        }
        if (quad == 0) { mlsh[2 * nl] = m_; mlsh[2 * nl + 1] = l_; }
    }
    __syncthreads();
    if (grp == 0) {
        float m1 = mlsh[2 * nl], l1 = mlsh[2 * nl + 1];
        float mm = fmaxf(m_, m1);
        float w0 = exp2f(m_ - mm), w1 = exp2f(m1 - mm);
        float inv = 1.0f / (l_ * w0 + l1 * w1);
        float a0 = w0 * inv, a1 = w1 * inv;
#pragma unroll
        for (int ct = 0; ct < 8; ct++) {
            int s = (ct * 4 + quad) ^ (nl & 7);
            f32x4 o1 = *(const f32x4*)&olds[nl * 128 + s * 4];
            uint2 pk;
            pk.x = (u32)f2bf(oacc[ct][0] * a0 + o1[0] * a1) |
                   ((u32)f2bf(oacc[ct][1] * a0 + o1[1] * a1) << 16);
            pk.y = (u32)f2bf(oacc[ct][2] * a0 + o1[2] * a1) |
                   ((u32)f2bf(oacc[ct][3] * a0 + o1[3] * a1) << 16);
            *(uint2*)&y_lds[nl * 136 + ct * 16 + quad * 4] = pk;
        }
    }
    __syncthreads();

    // final conv on 8 waves: group = co half, wl = n sub-tile
    bf16x8 af[4];
#pragma unroll
    for (int ks = 0; ks < 4; ks++)
        af[ks] = *(const bf16x8*)&y_lds[nl * 136 + ks * 32 + quad * 8];

#pragma unroll
    for (int ct = 0; ct < 8; ct++) {
        int co = grp * 128 + ct * 16 + l15;
        f32x4 a = (f32x4){0.f, 0.f, 0.f, 0.f};
#pragma unroll
        for (int ks = 0; ks < 4; ks++) {
            bf16x8 bf = *(const bf16x8*)&Wws[(size_t)co * kCI + ks * 32 + quad * 8];
            a = __builtin_amdgcn_mfma_f32_16x16x32_bf16(af[ks], bf, a, 0, 0, 0);
        }
        float bbv = bb[co];
        size_t base = (size_t)(b * kC + co) * kN + n0 + wl * 16 + quad * 4;
        float4 vv = *(const float4*)&v[base];
        float4 ov;
        ov.x = a[0] + bbv + vv.x;
        ov.y = a[1] + bbv + vv.y;
        ov.z = a[2] + bbv + vv.z;
        ov.w = a[3] + bbv + vv.w;
        *(float4*)&out[base] = ov;
    }
}

// ---------------------------------------------------------------------------
extern "C" void kernel_launch(void* const* d_in, const int* in_sizes, int n_in,
                              void* d_out, int out_size, void* d_ws, size_t ws_size,
                              hipStream_t stream) {
    (void)in_sizes; (void)n_in; (void)out_size; (void)ws_size;
    const float* q     = (const float*)d_in[0];
    const float* k     = (const float*)d_in[1];
    const float* v     = (const float*)d_in[2];
    const float* Wg    = (const float*)d_in[3];
    const float* bg    = (const float*)d_in[4];
    const float* Wth   = (const float*)d_in[5];
    const float* bth   = (const float*)d_in[6];
    const float* Wph   = (const float*)d_in[7];
    const float* bph   = (const float*)d_in[8];
    const float* Ww    = (const float*)d_in[9];
    const float* bw    = (const float*)d_in[10];
    const float* gamma = (const float*)d_in[11];
    const float* beta  = (const float*)d_in[12];
    const float* mean  = (const float*)d_in[13];
    const float* var   = (const float*)d_in[14];
    float* out = (float*)d_out;

    u16* wsu = (u16*)d_ws;
    u16*   theta = wsu;                       // 4M u16 (8MB)
    u16*   phi   = theta + 4194304;           // 1M u16 (2MB)
    u16*   gbuf  = phi + 1048576;             // 1M u16 (2MB)
    u16*   Wthb  = gbuf + 1048576;
    u16*   Wphb  = Wthb + 32768;
    u16*   Wgb   = Wphb + 32768;
    u16*   Wwsb  = Wgb + 32768;
    float* bbuf  = (float*)(Wwsb + 32768);    // 256 f32
    float* bthl  = bbuf + 256;                // 128 f32

    prep_kernel<<<dim3(512), 256, 0, stream>>>(Wth, bth, Wph, Wg, Ww, bw, gamma, beta,
                                               mean, var, Wthb, Wphb, Wgb, Wwsb,
                                               bbuf, bthl);
    convs_kernel<<<dim3(96, 8), 256, 0, stream>>>(q, k, v, Wthb, Wphb, Wgb,
                                                  bthl, bph, bg, theta, phi, gbuf);
    attn_kernel<<<dim3(64, 8), 512, 0, stream>>>(theta, phi, gbuf, Wwsb, bbuf, v, out);
}